// Round 3
// baseline (244.788 us; speedup 1.0000x reference)
//
#include <hip/hip_runtime.h>
#include <hip/hip_fp16.h>
#include <stdint.h>

#define NB     256     // batch
#define NI     1152    // input capsules
#define DI     8       // input capsule dim
#define NO     10      // output capsules
#define NK     16      // output capsule dim
#define NCHUNK 18      // NI / 64
#define XPAD   9

// ws layout (uint32 units):
//   plane h=0: u_hat fp16 k=0..7   [b][c18][o][il64][k2q4]   11,796,480 u32
//   plane h=1: u_hat fp16 k=8..15  (same shape)
//   s0 fp32 [b][o][k]  at S0_OFF_U32
#define PLANE_U32  11796480u
#define S0_OFF_U32 23592960u
#define WS_NEED_BYTES (94371840ull + 163840ull)

// ---------------------------------------------------------------------------
// Kernel A: u_hat = einsum('bid,iokd->biok') -> fp16 planes; s0 = 0.1*sum_i u
// grid (36 c-chunks of 32 i, 16 b-tiles of 16 b), 320 thr = (o10, il32)
// ---------------------------------------------------------------------------
__global__ __launch_bounds__(320)
void uhat_kernel(const float* __restrict__ x, const float* __restrict__ W,
                 uint32_t* __restrict__ ws)
{
    __shared__ float x_lds[16 * 32 * XPAD];   // [bb][il][d] pad 9 -> 18.4 KB

    const int c   = blockIdx.x;          // 0..35
    const int b0  = blockIdx.y * 16;
    const int tid = threadIdx.x;
    const int o   = tid >> 5;            // 0..9
    const int il  = tid & 31;            // 0..31

    for (int idx = tid; idx < 16 * 256; idx += 320) {
        const int bb = idx >> 8, r = idx & 255;
        x_lds[bb * (32 * XPAD) + (r >> 3) * XPAD + (r & 7)] =
            x[(size_t)(b0 + bb) * (NI * DI) + c * 256 + r];
    }
    __syncthreads();

    const int i = c * 32 + il;
    const float4* wp = reinterpret_cast<const float4*>(W + ((size_t)i * NO + o) * (NK * DI));
    float* s0f = reinterpret_cast<float*>(ws + S0_OFF_U32);

    const int cB   = i >> 6;
    const int il64 = i & 63;

#pragma unroll
    for (int h = 0; h < 2; ++h) {          // k = h*8 + kk
        float4 wr[16];
#pragma unroll
        for (int t = 0; t < 16; ++t) wr[t] = wp[h * 16 + t];

        for (int bb = 0; bb < 16; ++bb) {
            float xr[DI];
#pragma unroll
            for (int d = 0; d < DI; ++d) xr[d] = x_lds[bb * (32 * XPAD) + il * XPAD + d];

            float u[8];
#pragma unroll
            for (int kk = 0; kk < 8; ++kk) {
                const float4 w0 = wr[2 * kk], w1 = wr[2 * kk + 1];
                u[kk] = w0.x * xr[0] + w0.y * xr[1] + w0.z * xr[2] + w0.w * xr[3] +
                        w1.x * xr[4] + w1.y * xr[5] + w1.z * xr[6] + w1.w * xr[7];
            }

            uint32_t pk[4];
#pragma unroll
            for (int t = 0; t < 4; ++t) {
                union { __half2 h2; uint32_t w; } cv;
                cv.h2 = __float22half2_rn(make_float2(u[2 * t], u[2 * t + 1]));
                pk[t] = cv.w;
            }
            const int b = b0 + bb;
            // dense per-plane store: lane stride exactly 16B
            const size_t base = (size_t)h * PLANE_U32 +
                ((((size_t)b * NCHUNK + cB) * NO + o) * 64 + il64) * 4;
            *reinterpret_cast<uint4*>(ws + base) = make_uint4(pk[0], pk[1], pk[2], pk[3]);

            float r8[8];
#pragma unroll
            for (int kk = 0; kk < 8; ++kk) r8[kk] = u[kk];
#pragma unroll
            for (int m = 16; m >= 1; m >>= 1)
#pragma unroll
                for (int kk = 0; kk < 8; ++kk) r8[kk] += __shfl_xor(r8[kk], m, 64);
            if (il == 0) {
#pragma unroll
                for (int kk = 0; kk < 8; ++kk)
                    atomicAdd(&s0f[(size_t)b * (NO * NK) + o * NK + h * 8 + kk], 0.1f * r8[kk]);
            }
        }
    }
}

// ---------------------------------------------------------------------------
// Kernel B: routing, laneized. grid 256 (one block per b), 1024 thr = 16 waves.
// wave w owns i in [w*72, w*72+72) as 9 sets of 8; lane l: ii=l>>3, k2=l&7
// (k-pair 2k2, 2k2+1). Softmax over o is thread-local -> no barriers in loop.
// ---------------------------------------------------------------------------
__global__ __launch_bounds__(1024)
void route_kernel(const float* __restrict__ bias, float* __restrict__ out,
                  const uint32_t* __restrict__ ws)
{
    __shared__ float v_lds[NO * NK];           // 640 B
    __shared__ float s_red[16][NO * NK];       // 10.2 KB
    __shared__ float blog_lds[NI * NO];        // 46.1 KB (wave-private rows)

    const int tid = threadIdx.x;
    const int b   = blockIdx.x;
    const int w   = tid >> 6;
    const int l   = tid & 63;
    const int ii  = l >> 3;
    const int k2  = l & 7;
    const int k0  = k2 * 2;
    const int h   = k2 >> 2;
    const int k2q = k2 & 3;

    // ---- prologue: v0 = squash(s0 + bias) ----
    if (tid < NO * NK) {
        const float* s0f = reinterpret_cast<const float*>(ws + S0_OFF_U32);
        float sv = s0f[(size_t)b * (NO * NK) + tid] + bias[tid];
        float sq = sv * sv;
#pragma unroll
        for (int m = 8; m >= 1; m >>= 1) sq += __shfl_xor(sq, m, 64);
        const float scale = sq / (1.f + sq) / sqrtf(sq + 1e-9f);
        v_lds[tid] = scale * sv;
    }
    __syncthreads();

    for (int it = 0; it < 2; ++it) {
        float vk0[NO], vk1[NO];
#pragma unroll
        for (int o = 0; o < NO; ++o) {
            vk0[o] = v_lds[o * NK + k0];
            vk1[o] = v_lds[o * NK + k0 + 1];
        }

        float s0a[NO], s1a[NO];
#pragma unroll
        for (int o = 0; o < NO; ++o) { s0a[o] = 0.f; s1a[o] = 0.f; }

        for (int s = 0; s < 9; ++s) {
            const int i    = w * 72 + s * 8 + ii;
            const int cch  = i >> 6;
            const int il64 = i & 63;
            const uint32_t* up = ws + (size_t)h * PLANE_U32 +
                (((size_t)b * NCHUNK + cch) * NO * 64 + il64) * 4 + k2q;

            uint32_t uu[NO];
#pragma unroll
            for (int o = 0; o < NO; ++o) uu[o] = up[o * 256];

            float a[NO];
#pragma unroll
            for (int o = 0; o < NO; ++o) {
                union { uint32_t u; __half2 h2; } cv; cv.u = uu[o];
                const float2 f = __half22float2(cv.h2);
                a[o] = vk0[o] * f.x + vk1[o] * f.y;
            }
            // sum over the 16 k (8 k2-lanes x 2): all lanes end with full dot
#pragma unroll
            for (int m = 1; m <= 4; m <<= 1)
#pragma unroll
                for (int o = 0; o < NO; ++o) a[o] += __shfl_xor(a[o], m, 64);

            const int row = i * NO;
            if (it == 0) {
                // write blog (wave-private region, no barrier needed);
                // static-index select to avoid scratch (rule #20)
                float w0v = 0.f, w1v = 0.f;
#pragma unroll
                for (int o = 0; o < 8; ++o) if (k2 == o) w0v = a[o];
#pragma unroll
                for (int o = 0; o < 2; ++o) if (k2 == o) w1v = a[8 + o];
                blog_lds[row + k2] = w0v;
                if (k2 < 2) blog_lds[row + 8 + k2] = w1v;
            } else {
#pragma unroll
                for (int o = 0; o < NO; ++o) a[o] += blog_lds[row + o];
            }

            // thread-local softmax over o (|logit| <~ 20 -> no max-sub needed)
            float den = 0.f;
#pragma unroll
            for (int o = 0; o < NO; ++o) { a[o] = __expf(a[o]); den += a[o]; }
            const float rden = 1.f / den;
#pragma unroll
            for (int o = 0; o < NO; ++o) {
                const float cc = a[o] * rden;
                union { uint32_t u; __half2 h2; } cv; cv.u = uu[o];
                const float2 f = __half22float2(cv.h2);
                s0a[o] += cc * f.x;
                s1a[o] += cc * f.y;
            }
        }

        // reduce s over the 8 ii positions
#pragma unroll
        for (int m = 8; m <= 32; m <<= 1)
#pragma unroll
            for (int o = 0; o < NO; ++o) {
                s0a[o] += __shfl_xor(s0a[o], m, 64);
                s1a[o] += __shfl_xor(s1a[o], m, 64);
            }
        if (ii == 0) {
#pragma unroll
            for (int o = 0; o < NO; ++o) {
                s_red[w][o * NK + k0]     = s0a[o];
                s_red[w][o * NK + k0 + 1] = s1a[o];
            }
        }
        __syncthreads();

        // cross-wave reduce + squash (threads 0..159: o = tid>>4, k = tid&15)
        if (tid < NO * NK) {
            float sv = bias[tid];
#pragma unroll
            for (int ww = 0; ww < 16; ++ww) sv += s_red[ww][tid];
            float sq = sv * sv;
#pragma unroll
            for (int m = 8; m >= 1; m >>= 1) sq += __shfl_xor(sq, m, 64);
            const float scale = sq / (1.f + sq) / sqrtf(sq + 1e-9f);
            if (it == 1) out[(size_t)b * (NO * NK) + tid] = scale * sv;
            else         v_lds[tid] = scale * sv;
        }
        __syncthreads();
    }
}

// ---------------------------------------------------------------------------
// Fallback (ws too small): monolithic, recompute u_hat per pass
// ---------------------------------------------------------------------------
__device__ __forceinline__ void compute_uhat_fb(int i, int o,
        const float* x_lds, const float* __restrict__ W, float* u)
{
    float xr[DI];
#pragma unroll
    for (int d = 0; d < DI; ++d) xr[d] = x_lds[i * XPAD + d];
    const float4* wp = reinterpret_cast<const float4*>(W + (size_t)(i * NO + o) * (NK * DI));
#pragma unroll
    for (int k = 0; k < NK; ++k) {
        float4 w0 = wp[2 * k], w1 = wp[2 * k + 1];
        u[k] = w0.x * xr[0] + w0.y * xr[1] + w0.z * xr[2] + w0.w * xr[3] +
               w1.x * xr[4] + w1.y * xr[5] + w1.z * xr[6] + w1.w * xr[7];
    }
}

__global__ __launch_bounds__(640)
void digitcaps_fallback(const float* __restrict__ x, const float* __restrict__ W,
                        const float* __restrict__ bias, float* __restrict__ out)
{
    __shared__ float x_lds[NI * XPAD];
    __shared__ float blog_lds[64][NO + 1];
    __shared__ float v_lds[NO][NK];
    const int b = blockIdx.x, tid = threadIdx.x;
    const int o = tid >> 6, il = tid & 63;
    const float* xb = x + (size_t)b * (NI * DI);
    for (int idx = tid; idx < NI * DI; idx += 640)
        x_lds[(idx >> 3) * XPAD + (idx & 7)] = xb[idx];
    float bias_r[NK];
#pragma unroll
    for (int k = 0; k < NK; ++k) bias_r[k] = bias[o * NK + k];
    __syncthreads();
    float blog[NCHUNK], s_acc[NK];
    auto finish = [&](int it) {
#pragma unroll
        for (int off = 32; off >= 1; off >>= 1)
#pragma unroll
            for (int k = 0; k < NK; ++k) s_acc[k] += __shfl_xor(s_acc[k], off, 64);
        float sv[NK], sq = 0.f;
#pragma unroll
        for (int k = 0; k < NK; ++k) { sv[k] = s_acc[k] + bias_r[k]; sq += sv[k] * sv[k]; }
        const float scale = sq / (1.f + sq) / sqrtf(sq + 1e-9f);
        if (il == 0) {
            if (it == 2) {
#pragma unroll
                for (int k = 0; k < NK; ++k) out[(size_t)b * 160 + o * NK + k] = scale * sv[k];
            } else {
#pragma unroll
                for (int k = 0; k < NK; ++k) v_lds[o][k] = scale * sv[k];
            }
        }
    };
#pragma unroll
    for (int k = 0; k < NK; ++k) s_acc[k] = 0.f;
    for (int c = 0; c < NCHUNK; ++c) {
        float u[NK];
        compute_uhat_fb(c * 64 + il, o, x_lds, W, u);
#pragma unroll
        for (int k = 0; k < NK; ++k) s_acc[k] += u[k];
        blog[c] = 0.f;
    }
#pragma unroll
    for (int k = 0; k < NK; ++k) s_acc[k] *= 0.1f;
    finish(0);
    __syncthreads();
    for (int it = 1; it <= 2; ++it) {
#pragma unroll
        for (int k = 0; k < NK; ++k) s_acc[k] = 0.f;
        for (int c = 0; c < NCHUNK; ++c) {
            const int i = c * 64 + il;
            float u[NK];
            compute_uhat_fb(i, o, x_lds, W, u);
            float a = 0.f;
#pragma unroll
            for (int k = 0; k < NK; ++k) a += v_lds[o][k] * u[k];
            blog[c] += a;
            __syncthreads();
            blog_lds[il][o] = blog[c];
            __syncthreads();
            float m = blog_lds[il][0];
#pragma unroll
            for (int oo = 1; oo < NO; ++oo) m = fmaxf(m, blog_lds[il][oo]);
            float den = 0.f;
#pragma unroll
            for (int oo = 0; oo < NO; ++oo) den += __expf(blog_lds[il][oo] - m);
            const float cv = __expf(blog[c] - m) / den;
#pragma unroll
            for (int k = 0; k < NK; ++k) s_acc[k] += cv * u[k];
        }
        finish(it);
        __syncthreads();
    }
}

extern "C" void kernel_launch(void* const* d_in, const int* in_sizes, int n_in,
                              void* d_out, int out_size, void* d_ws, size_t ws_size,
                              hipStream_t stream)
{
    const float* x    = (const float*)d_in[0];  // [256,1152,8]
    const float* W    = (const float*)d_in[1];  // [1152,10,16,8]
    const float* bias = (const float*)d_in[2];  // [10,16]
    float* out = (float*)d_out;                 // [256,10,16]

    if (ws_size >= WS_NEED_BYTES) {
        hipMemsetAsync((char*)d_ws + (size_t)S0_OFF_U32 * 4, 0, NB * NO * NK * 4, stream);
        uhat_kernel<<<dim3(36, 16), 320, 0, stream>>>(x, W, (uint32_t*)d_ws);
        route_kernel<<<NB, 1024, 0, stream>>>(bias, out, (const uint32_t*)d_ws);
    } else {
        digitcaps_fallback<<<NB, 640, 0, stream>>>(x, W, bias, out);
    }
}